// Round 1
// baseline (376.577 us; speedup 1.0000x reference)
//
#include <hip/hip_runtime.h>

// Problem constants (from reference): B=8, N_IN=256, N=8192, D=64, K=512
#define B_SZ   8
#define NIN    256
#define NCOL   8192
#define DDIM   64
#define KCODES 512
#define ZQ_ELEMS (8ull * 64ull * 8192ull)   // 4,194,304 floats, then 512 hist floats

// ---------------------------------------------------------------------------
// Prep kernel: transpose W (D x NIN) -> Wt (NIN x D) so the main loop's
// wave-uniform W reads are contiguous (s_load_dwordx16-friendly);
// precompute emb_sq[k] = sum_d emb[k,d]^2; initialize hist output = ind_hist.
// ---------------------------------------------------------------------------
__global__ __launch_bounds__(256) void vq_prep(const float* __restrict__ W,
                                               const float* __restrict__ emb,
                                               const float* __restrict__ ind_hist,
                                               float* __restrict__ Wt,
                                               float* __restrict__ emb_sq,
                                               float* __restrict__ hist_out)
{
    int t = blockIdx.x * 256 + threadIdx.x;
    if (t < NIN * DDIM) {
        int i = t >> 6;      // row of Wt  (0..255)
        int d = t & 63;      // col of Wt  (0..63)
        Wt[t] = W[d * NIN + i];
    }
    if (t < KCODES) {
        const float* __restrict__ ek = emb + t * DDIM;
        float s = 0.f;
        #pragma unroll
        for (int d = 0; d < DDIM; ++d) s = fmaf(ek[d], ek[d], s);
        emb_sq[t] = s;
        hist_out[t] = ind_hist[t];
    }
}

// ---------------------------------------------------------------------------
// Main fused kernel: one thread per output column (b, n).
//   1. conv: ze[d] = sum_i Wt[i][d] * z[b,i,n]   (64 VGPR accumulators,
//      z coalesced across lanes, Wt wave-uniform -> scalar loads)
//   2. nearest code: argmin_k (ze_sq + emb_sq[k] - 2*dot(emb[k], ze)),
//      first-min tie-break (strict <, ascending k) to match jnp.argmin
//   3. write zq straight-through: out = ze + (emb[k*] - ze)
//   4. histogram: atomicAdd(+1.0f) into hist[k*]
// ---------------------------------------------------------------------------
__global__ __launch_bounds__(256) void vq_main(const float* __restrict__ z,
                                               const float* __restrict__ Wt,
                                               const float* __restrict__ emb,
                                               const float* __restrict__ emb_sq,
                                               float* __restrict__ out,
                                               float* __restrict__ hist)
{
    const int c = blockIdx.x * 256 + threadIdx.x;   // global column id
    const int b = c >> 13;                          // / 8192
    const int n = c & (NCOL - 1);

    const float* __restrict__ zp = z + (size_t)b * NIN * NCOL + n;

    float ze[DDIM];
    #pragma unroll
    for (int d = 0; d < DDIM; ++d) ze[d] = 0.f;

    // ---- 1x1 conv: 256 * 64 FMAs per thread ----
    for (int i = 0; i < NIN; i += 4) {
        float z0 = zp[(size_t)(i + 0) * NCOL];
        float z1 = zp[(size_t)(i + 1) * NCOL];
        float z2 = zp[(size_t)(i + 2) * NCOL];
        float z3 = zp[(size_t)(i + 3) * NCOL];
        #pragma unroll
        for (int d = 0; d < DDIM; ++d) {
            float a = ze[d];
            a = fmaf(Wt[(i + 0) * DDIM + d], z0, a);
            a = fmaf(Wt[(i + 1) * DDIM + d], z1, a);
            a = fmaf(Wt[(i + 2) * DDIM + d], z2, a);
            a = fmaf(Wt[(i + 3) * DDIM + d], z3, a);
            ze[d] = a;
        }
    }

    // ---- ze_sq ----
    float zesq = 0.f;
    #pragma unroll
    for (int d = 0; d < DDIM; ++d) zesq = fmaf(ze[d], ze[d], zesq);

    // ---- nearest-code search: 512 * 64 FMAs per thread ----
    float best = 3.4e38f;
    int bestk = 0;
    for (int k = 0; k < KCODES; ++k) {
        const float* __restrict__ ek = emb + k * DDIM;   // wave-uniform
        float cr = 0.f;
        #pragma unroll
        for (int d = 0; d < DDIM; ++d) cr = fmaf(ek[d], ze[d], cr);
        float dist = (zesq + emb_sq[k]) - 2.0f * cr;     // matches ref formula order
        if (dist < best) { best = dist; bestk = k; }     // first-min tie-break
    }

    // ---- histogram ----
    atomicAdd(hist + bestk, 1.0f);

    // ---- straight-through output: ze + (zq - ze) ----
    const float4* __restrict__ eq4 =
        reinterpret_cast<const float4*>(emb + (size_t)bestk * DDIM);
    float* __restrict__ op = out + (size_t)b * DDIM * NCOL + n;
    #pragma unroll
    for (int q = 0; q < DDIM / 4; ++q) {
        float4 e = eq4[q];   // per-thread gather, L1/L2-resident (emb = 128 KiB)
        op[(size_t)(4 * q + 0) * NCOL] = ze[4 * q + 0] + (e.x - ze[4 * q + 0]);
        op[(size_t)(4 * q + 1) * NCOL] = ze[4 * q + 1] + (e.y - ze[4 * q + 1]);
        op[(size_t)(4 * q + 2) * NCOL] = ze[4 * q + 2] + (e.z - ze[4 * q + 2]);
        op[(size_t)(4 * q + 3) * NCOL] = ze[4 * q + 3] + (e.w - ze[4 * q + 3]);
    }
}

// ---------------------------------------------------------------------------
extern "C" void kernel_launch(void* const* d_in, const int* in_sizes, int n_in,
                              void* d_out, int out_size, void* d_ws, size_t ws_size,
                              hipStream_t stream)
{
    const float* z        = (const float*)d_in[0];  // (8, 256, 8192)
    const float* W        = (const float*)d_in[1];  // (64, 256)
    const float* emb      = (const float*)d_in[2];  // (512, 64)
    const float* ind_hist = (const float*)d_in[3];  // (512,)

    float* out  = (float*)d_out;                    // zq (8,64,8192) then hist (512,)
    float* hist = out + ZQ_ELEMS;

    float* Wt     = (float*)d_ws;                   // NIN*DDIM floats
    float* emb_sq = Wt + NIN * DDIM;                // KCODES floats

    // prep: transpose W, emb_sq, hist init (re-run every call: deterministic)
    hipLaunchKernelGGL(vq_prep, dim3(64), dim3(256), 0, stream,
                       W, emb, ind_hist, Wt, emb_sq, hist);

    // main: 65536 columns, 1 thread each
    hipLaunchKernelGGL(vq_main, dim3((B_SZ * NCOL) / 256), dim3(256), 0, stream,
                       z, Wt, emb, emb_sq, out, hist);
}